// Round 2
// baseline (298.715 us; speedup 1.0000x reference)
//
#include <hip/hip_runtime.h>
#include <math.h>

#ifndef M_PI
#define M_PI 3.14159265358979323846
#endif

#define Hh   256
#define Ww   1216
#define HWsz (Hh * Ww)          // 311296
#define Bb   32
#define KH   30
#define KW   49
#define NTAP (KH * KW)          // 1470
#define SHs  16
#define SWs  48
#define NPB  (SHs * SWs)        // 768 points per batch
#define NPTS (Bb * NPB)         // 24576
#define OUT0 (Bb * HWsz)        // 9961472
#define OUT1 (Bb * HWsz * 2)    // 19922944

// Bilinear tap matching reference gather(): mask on float coords, clip-then-trunc index.
__device__ __forceinline__ float samp4(const float* __restrict__ g, float yc, float xc, float w) {
#pragma clang fp contract(off)
    bool m = (yc >= 0.0f) && (yc <= 255.0f) && (xc >= 0.0f) && (xc <= 1215.0f);
    float ycl = fminf(fmaxf(yc, 0.0f), 255.0f);
    float xcl = fminf(fmaxf(xc, 0.0f), 1215.0f);
    int yi = (int)ycl, xi = (int)xcl;
    float wm = m ? w : 0.0f;
    return g[yi * Ww + xi] * wm;
}

// One wave per (batch, i, j) sample point: 30x49 Gaussian window dot-product on both
// channels (fp64 accumulate, fp32 weights identical to numpy's cast), then grid add,
// bilinear gather from gt, and scatter-coordinate computation.
__global__ __launch_bounds__(256) void k_conv_sample(
    const float* __restrict__ gt, const float* __restrict__ dvf,
    float* __restrict__ out2, float* __restrict__ vbuf, int* __restrict__ rcbuf)
{
#pragma clang fp contract(off)
    __shared__ double s_gh[KH];
    __shared__ double s_gw[KW];
    __shared__ double s_invS;
    __shared__ float  s_w[NTAP];
    const int tid = threadIdx.x;

    if (tid < KH) {
        const double sh_ = (2.0 * 256.0 / 17.0) / 3.0;     // mirrors 2*H/(SH+1)/3.0
        double u = ((double)tid - 14.5) / sh_;             // (kh-1)/2 = 14.5
        s_gh[tid] = exp(-(u * u) / 2.0) / (sh_ * sqrt(2.0 * M_PI));
    } else if (tid >= 64 && tid < 64 + KW) {
        int t = tid - 64;
        const double sw_ = (2.0 * 1216.0 / 49.0) / 3.0;
        double u = ((double)t - 24.0) / sw_;               // (kw-1)/2 = 24.0
        s_gw[t] = exp(-(u * u) / 2.0) / (sw_ * sqrt(2.0 * M_PI));
    }
    __syncthreads();
    if (tid == 0) {
        double a = 0.0, c = 0.0;
        for (int t = 0; t < KH; ++t) a += s_gh[t];
        for (int t = 0; t < KW; ++t) c += s_gw[t];
        s_invS = 1.0 / (a * c);                            // 1/k.sum(); one fp64 divide
    }
    __syncthreads();
    {
        const double invS = s_invS;
        for (int t = tid; t < NTAP; t += 256)
            s_w[t] = (float)((s_gh[t / KW] * s_gw[t % KW]) * invS);  // fp64 -> fp32 cast like numpy
    }
    __syncthreads();

    const int wave = tid >> 6, lane = tid & 63;
    const int pt = blockIdx.x * 4 + wave;                  // grid sized exactly: pt < NPTS
    const int b = pt / NPB, p = pt - b * NPB;
    const int i = p / SWs, j = p - i * SWs;
    const int y0r = (i * 227) >> 4;                        // arange(16)*227//16
    const int x0c = (j * 1168) / 48;                       // arange(48)*1168//48
    const float* c0 = dvf + (size_t)b * (2 * HWsz) + y0r * Ww + x0c;
    const float* c1 = c0 + HWsz;

    double a0 = 0.0, a1 = 0.0;
    for (int t = lane; t < NTAP; t += 64) {
        int dy = t / KW, dx = t - dy * KW;
        int off = dy * Ww + dx;
        double w = (double)s_w[t];
        a0 += w * (double)c0[off];
        a1 += w * (double)c1[off];
    }
    for (int o = 32; o > 0; o >>= 1) {
        a0 += __shfl_down(a0, o);
        a1 += __shfl_down(a1, o);
    }

    if (lane == 0) {
        float sx = (float)a0, sy = (float)a1;              // smoothed (fp32, like ref conv out)
        // numpy linspace semantics: y = j*step + start, endpoint forced to stop.
        const double startw = -(47.0 / 48.0), stopw = 47.0 / 48.0;
        const double starth = -(15.0 / 16.0), stoph = 15.0 / 16.0;
        const double stepw = (stopw - startw) / 47.0;
        const double steph = (stoph - starth) / 15.0;
        float gwl = (j == SWs - 1) ? (float)stopw : (float)((double)j * stepw + startw);
        float ghl = (i == SHs - 1) ? (float)stoph : (float)((double)i * steph + starth);
        float gx = sx + gwl;
        float gy = sy + ghl;

        float* o2 = out2 + ((size_t)(b * SHs + i) * SWs + j) * 2;
        o2[0] = gx; o2[1] = gy;

        // bilinear: x = (gx+1)*W/2 - 0.5 with reference op order
        const float* gtb = gt + (size_t)b * HWsz;
        float xw = (gx + 1.0f) * 1216.0f; xw = xw / 2.0f; xw = xw - 0.5f;
        float yw = (gy + 1.0f) * 256.0f;  yw = yw / 2.0f; yw = yw - 0.5f;
        float x0f = floorf(xw), y0f = floorf(yw);
        float x1f = x0f + 1.0f, y1f = y0f + 1.0f;
        float wx1 = xw - x0f, wx0 = 1.0f - wx1;
        float wy1 = yw - y0f, wy0 = 1.0f - wy1;
        float v = samp4(gtb, y0f, x0f, wy0 * wx0) + samp4(gtb, y0f, x1f, wy0 * wx1)
                + samp4(gtb, y1f, x0f, wy1 * wx0) + samp4(gtb, y1f, x1f, wy1 * wx1);

        // scatter coords: trunc toward zero (astype(int32)) THEN clip
        float rf = (gy + 1.0f) / 2.0f * 256.0f;
        float cf = (gx + 1.0f) / 2.0f * 1216.0f;
        int row = (int)rf; row = row < 0 ? 0 : (row > Hh - 1 ? Hh - 1 : row);
        int col = (int)cf; col = col < 0 ? 0 : (col > Ww - 1 ? Ww - 1 : col);
        vbuf[pt]  = v;
        rcbuf[pt] = (row << 16) | col;
    }
}

// Parallel last-write-wins scatter: point p writes iff no later point p' (same batch)
// targets the same (row,col). Identical result to the serial in-order replay, but all
// 768 points resolve concurrently via an LDS conflict scan. Rows < 96 skipped
// (reference zeroes them after the scatter).
__global__ __launch_bounds__(256) void k_scatter(
    const float* __restrict__ vbuf, const int* __restrict__ rcbuf, float* __restrict__ out0)
{
    __shared__ float sv[NPB];
    __shared__ int   sr[NPB];
    const int b = blockIdx.x, tid = threadIdx.x;
    for (int t = tid; t < NPB; t += 256) {
        sv[t] = vbuf[b * NPB + t];
        sr[t] = rcbuf[b * NPB + t];
    }
    __syncthreads();
    float* o = out0 + (size_t)b * HWsz;
    for (int p = tid; p < NPB; p += 256) {
        int rc = sr[p];
        int r = rc >> 16;
        if (r < 96) continue;
        bool win = true;
        for (int q = p + 1; q < NPB; ++q) {
            if (sr[q] == rc) { win = false; break; }
        }
        if (win) o[r * Ww + (rc & 0xffff)] = sv[p];
    }
}

// Fused: zero-fill out0 (one float4 per thread — exactly covers [B,1,H,W]) and
// NCHW [B,2,H,W] -> NHWC [B,H,W,2] transpose, 4 pixels (32B out) per thread.
__global__ __launch_bounds__(256) void k_transpose_zero(
    const float* __restrict__ dvf, float* __restrict__ out1, float* __restrict__ out0)
{
    const size_t idx = (size_t)blockIdx.x * 256 + threadIdx.x;   // over Bb * HWsz/4
    ((float4*)out0)[idx] = make_float4(0.0f, 0.0f, 0.0f, 0.0f);
    const int b = (int)(idx / (HWsz / 4));
    const int r = (int)(idx - (size_t)b * (HWsz / 4));
    const float4* p0 = (const float4*)(dvf + (size_t)b * 2 * HWsz);
    const float4* p1 = (const float4*)(dvf + (size_t)b * 2 * HWsz + HWsz);
    float4 a = p0[r], c = p1[r];
    float4* o = (float4*)(out1 + ((size_t)b * HWsz + (size_t)r * 4) * 2);
    o[0] = make_float4(a.x, c.x, a.y, c.y);
    o[1] = make_float4(a.z, c.z, a.w, c.w);
}

extern "C" void kernel_launch(void* const* d_in, const int* in_sizes, int n_in,
                              void* d_out, int out_size, void* d_ws, size_t ws_size,
                              hipStream_t stream) {
    const float* gt  = (const float*)d_in[0];
    const float* dvf = (const float*)d_in[1];
    float* out0 = (float*)d_out;
    float* out1 = out0 + OUT0;
    float* out2 = out1 + OUT1;
    float* vbuf  = (float*)d_ws;          // NPTS floats
    int*   rcbuf = (int*)d_ws + NPTS;     // NPTS ints (total 192 KiB of ws)

    hipLaunchKernelGGL(k_conv_sample, dim3(NPTS / 4), dim3(256), 0, stream,
                       gt, dvf, out2, vbuf, rcbuf);
    hipLaunchKernelGGL(k_transpose_zero, dim3((Bb * (HWsz / 4)) / 256), dim3(256), 0, stream,
                       dvf, out1, out0);
    hipLaunchKernelGGL(k_scatter, dim3(Bb), dim3(256), 0, stream,
                       vbuf, rcbuf, out0);
}

// Round 4
// 293.527 us; speedup vs baseline: 1.0177x; 1.0177x over previous
//
#include <hip/hip_runtime.h>
#include <math.h>

#ifndef M_PI
#define M_PI 3.14159265358979323846
#endif

#define Hh   256
#define Ww   1216
#define HWsz (Hh * Ww)          // 311296
#define Bb   32
#define KH   30
#define KW   49
#define NTAP (KH * KW)          // 1470
#define SHs  16
#define SWs  48
#define NPB  (SHs * SWs)        // 768 points per batch
#define NPTS (Bb * NPB)         // 24576
#define OUT0 (Bb * HWsz)        // 9961472
#define OUT1 (Bb * HWsz * 2)    // 19922944

#define CONV_BLKS (NPTS / 4)            // 6144 blocks, 4 waves each = 1 wave/point
#define TPOS_BLKS (Bb * (HWsz / 4) / 256)  // 9728 blocks for transpose+zero

// Bilinear tap matching reference gather(): mask on float coords, clip-then-trunc index.
__device__ __forceinline__ float samp4(const float* __restrict__ g, float yc, float xc, float w) {
#pragma clang fp contract(off)
    bool m = (yc >= 0.0f) && (yc <= 255.0f) && (xc >= 0.0f) && (xc <= 1215.0f);
    float ycl = fminf(fmaxf(yc, 0.0f), 255.0f);
    float xcl = fminf(fmaxf(xc, 0.0f), 1215.0f);
    int yi = (int)ycl, xi = (int)xcl;
    float wm = m ? w : 0.0f;
    return g[yi * Ww + xi] * wm;
}

// Fused kernel. Blocks [0, CONV_BLKS): one wave per (batch,i,j) sample point —
// 30x49 Gaussian window dot product (fp64 accumulate, fp32 weights identical to
// numpy), grid add, bilinear gather, scatter-coordinate computation.
// Blocks [CONV_BLKS, CONV_BLKS+TPOS_BLKS): zero-fill out0 + NCHW->NHWC transpose.
// The two halves are independent; fusing saves a graph node and mixes
// latency-bound gather waves with BW-bound streaming waves on each CU.
__global__ __launch_bounds__(256) void k_fused(
    const float* __restrict__ gt, const float* __restrict__ dvf,
    float* __restrict__ out0, float* __restrict__ out1, float* __restrict__ out2,
    float* __restrict__ vbuf, int* __restrict__ rcbuf)
{
#pragma clang fp contract(off)
    const int tid = threadIdx.x;

    if (blockIdx.x >= CONV_BLKS) {
        // ---- transpose + zero path ----
        const size_t idx = (size_t)(blockIdx.x - CONV_BLKS) * 256 + tid;  // over Bb*HWsz/4
        ((float4*)out0)[idx] = make_float4(0.0f, 0.0f, 0.0f, 0.0f);
        const int b = (int)(idx / (HWsz / 4));
        const int r = (int)(idx - (size_t)b * (HWsz / 4));
        const float4* p0 = (const float4*)(dvf + (size_t)b * 2 * HWsz);
        const float4* p1 = (const float4*)(dvf + (size_t)b * 2 * HWsz + HWsz);
        float4 a = p0[r], c = p1[r];
        float4* o = (float4*)(out1 + ((size_t)b * HWsz + (size_t)r * 4) * 2);
        o[0] = make_float4(a.x, c.x, a.y, c.y);
        o[1] = make_float4(a.z, c.z, a.w, c.w);
        return;
    }

    // ---- conv + sample path ----
    __shared__ double s_gh[KH];
    __shared__ double s_gw[KW];
    __shared__ double s_invS;
    __shared__ float  s_w[NTAP];
    __shared__ int    s_off[NTAP];

    if (tid < KH) {
        const double sh_ = (2.0 * 256.0 / 17.0) / 3.0;     // mirrors 2*H/(SH+1)/3.0
        double u = ((double)tid - 14.5) / sh_;             // (kh-1)/2 = 14.5
        s_gh[tid] = exp(-(u * u) / 2.0) / (sh_ * sqrt(2.0 * M_PI));
    } else if (tid >= 64 && tid < 64 + KW) {
        int t = tid - 64;
        const double sw_ = (2.0 * 1216.0 / 49.0) / 3.0;
        double u = ((double)t - 24.0) / sw_;               // (kw-1)/2 = 24.0
        s_gw[t] = exp(-(u * u) / 2.0) / (sw_ * sqrt(2.0 * M_PI));
    }
    __syncthreads();
    if (tid == 0) {
        double a = 0.0, c = 0.0;
        for (int t = 0; t < KH; ++t) a += s_gh[t];
        for (int t = 0; t < KW; ++t) c += s_gw[t];
        s_invS = 1.0 / (a * c);                            // 1/k.sum(); one fp64 divide
    }
    __syncthreads();
    {
        const double invS = s_invS;
        for (int t = tid; t < NTAP; t += 256) {
            int dy = t / KW, dx = t - dy * KW;             // magic-mul, once per tap
            s_w[t]   = (float)((s_gh[dy] * s_gw[dx]) * invS);  // fp64->fp32 like numpy
            s_off[t] = dy * Ww + dx;
        }
    }
    __syncthreads();

    const int wave = tid >> 6, lane = tid & 63;
    const int pt = blockIdx.x * 4 + wave;                  // pt < NPTS exactly
    const int b = pt / NPB, p = pt - b * NPB;
    const int i = p / SWs, j = p - i * SWs;
    const int y0r = (i * 227) >> 4;                        // arange(16)*227//16
    const int x0c = (j * 1168) / 48;                       // arange(48)*1168//48
    const float* c0 = dvf + (size_t)b * (2 * HWsz) + y0r * Ww + x0c;
    const float* c1 = c0 + HWsz;

    double a0 = 0.0, a1 = 0.0;
    for (int t = lane; t < NTAP; t += 64) {
        int off = s_off[t];
        double w = (double)s_w[t];
        a0 += w * (double)c0[off];
        a1 += w * (double)c1[off];
    }
    for (int o = 32; o > 0; o >>= 1) {
        a0 += __shfl_down(a0, o);
        a1 += __shfl_down(a1, o);
    }

    if (lane == 0) {
        float sx = (float)a0, sy = (float)a1;              // smoothed (fp32, like ref conv out)
        // numpy linspace semantics: y = j*step + start, endpoint forced to stop.
        const double startw = -(47.0 / 48.0), stopw = 47.0 / 48.0;
        const double starth = -(15.0 / 16.0), stoph = 15.0 / 16.0;
        const double stepw = (stopw - startw) / 47.0;
        const double steph = (stoph - starth) / 15.0;
        float gwl = (j == SWs - 1) ? (float)stopw : (float)((double)j * stepw + startw);
        float ghl = (i == SHs - 1) ? (float)stoph : (float)((double)i * steph + starth);
        float gx = sx + gwl;
        float gy = sy + ghl;

        float* o2 = out2 + ((size_t)(b * SHs + i) * SWs + j) * 2;
        o2[0] = gx; o2[1] = gy;

        // bilinear: x = (gx+1)*W/2 - 0.5 with reference op order
        const float* gtb = gt + (size_t)b * HWsz;
        float xw = (gx + 1.0f) * 1216.0f; xw = xw / 2.0f; xw = xw - 0.5f;
        float yw = (gy + 1.0f) * 256.0f;  yw = yw / 2.0f; yw = yw - 0.5f;
        float x0f = floorf(xw), y0f = floorf(yw);
        float x1f = x0f + 1.0f, y1f = y0f + 1.0f;
        float wx1 = xw - x0f, wx0 = 1.0f - wx1;
        float wy1 = yw - y0f, wy0 = 1.0f - wy1;
        float v = samp4(gtb, y0f, x0f, wy0 * wx0) + samp4(gtb, y0f, x1f, wy0 * wx1)
                + samp4(gtb, y1f, x0f, wy1 * wx0) + samp4(gtb, y1f, x1f, wy1 * wx1);

        // scatter coords: trunc toward zero (astype(int32)) THEN clip
        float rf = (gy + 1.0f) / 2.0f * 256.0f;
        float cf = (gx + 1.0f) / 2.0f * 1216.0f;
        int row = (int)rf; row = row < 0 ? 0 : (row > Hh - 1 ? Hh - 1 : row);
        int col = (int)cf; col = col < 0 ? 0 : (col > Ww - 1 ? Ww - 1 : col);
        vbuf[pt]  = v;
        rcbuf[pt] = (row << 16) | col;
    }
}

// Parallel last-write-wins scatter: point p writes iff no later point p' (same batch)
// targets the same (row,col) — identical result to serial in-order replay. Rows < 96
// skipped (reference zeroes them after the scatter).
__global__ __launch_bounds__(256) void k_scatter(
    const float* __restrict__ vbuf, const int* __restrict__ rcbuf, float* __restrict__ out0)
{
    __shared__ float sv[NPB];
    __shared__ int   sr[NPB];
    const int b = blockIdx.x, tid = threadIdx.x;
    for (int t = tid; t < NPB; t += 256) {
        sv[t] = vbuf[b * NPB + t];
        sr[t] = rcbuf[b * NPB + t];
    }
    __syncthreads();
    float* o = out0 + (size_t)b * HWsz;
    for (int p = tid; p < NPB; p += 256) {
        int rc = sr[p];
        int r = rc >> 16;
        if (r < 96) continue;
        bool win = true;
        for (int q = p + 1; q < NPB; ++q) {
            if (sr[q] == rc) { win = false; break; }
        }
        if (win) o[r * Ww + (rc & 0xffff)] = sv[p];
    }
}

extern "C" void kernel_launch(void* const* d_in, const int* in_sizes, int n_in,
                              void* d_out, int out_size, void* d_ws, size_t ws_size,
                              hipStream_t stream) {
    const float* gt  = (const float*)d_in[0];
    const float* dvf = (const float*)d_in[1];
    float* out0 = (float*)d_out;
    float* out1 = out0 + OUT0;
    float* out2 = out1 + OUT1;
    float* vbuf  = (float*)d_ws;          // NPTS floats
    int*   rcbuf = (int*)d_ws + NPTS;     // NPTS ints (total 192 KiB of ws)

    hipLaunchKernelGGL(k_fused, dim3(CONV_BLKS + TPOS_BLKS), dim3(256), 0, stream,
                       gt, dvf, out0, out1, out2, vbuf, rcbuf);
    hipLaunchKernelGGL(k_scatter, dim3(Bb), dim3(256), 0, stream,
                       vbuf, rcbuf, out0);
}

// Round 5
// 283.728 us; speedup vs baseline: 1.0528x; 1.0345x over previous
//
#include <hip/hip_runtime.h>
#include <math.h>

#ifndef M_PI
#define M_PI 3.14159265358979323846
#endif

#define Hh   256
#define Ww   1216
#define HWsz (Hh * Ww)          // 311296
#define Bb   32
#define KH   30
#define KW   49
#define NTAP (KH * KW)          // 1470
#define SHs  16
#define SWs  48
#define NPB  (SHs * SWs)        // 768 points per batch
#define NPTS (Bb * NPB)         // 24576
#define OUT0 (Bb * HWsz)        // 9961472
#define OUT1 (Bb * HWsz * 2)    // 19922944

#define CONV_BLKS (NPTS / 4)               // 6144 blocks, 4 waves each = 1 wave/point
#define TPOS_BLKS (Bb * (HWsz / 4) / 256)  // 9728 blocks for transpose+zero

// Bilinear tap matching reference gather(): mask on float coords, clip-then-trunc index.
__device__ __forceinline__ float samp4(const float* __restrict__ g, float yc, float xc, float w) {
#pragma clang fp contract(off)
    bool m = (yc >= 0.0f) && (yc <= 255.0f) && (xc >= 0.0f) && (xc <= 1215.0f);
    float ycl = fminf(fmaxf(yc, 0.0f), 255.0f);
    float xcl = fminf(fmaxf(xc, 0.0f), 1215.0f);
    int yi = (int)ycl, xi = (int)xcl;
    float wm = m ? w : 0.0f;
    return g[yi * Ww + xi] * wm;
}

// One-block weight precompute: identical fp64 math to the previously-validated
// in-block version (device exp, serial sums, single divide, fp64->fp32 cast).
// Runs every call (d_ws is re-poisoned each timed iteration).
__global__ __launch_bounds__(256) void k_weights(float* __restrict__ wtab) {
    __shared__ double s_gh[KH];
    __shared__ double s_gw[KW];
    __shared__ double s_invS;
    const int tid = threadIdx.x;

    if (tid < KH) {
        const double sh_ = (2.0 * 256.0 / 17.0) / 3.0;     // mirrors 2*H/(SH+1)/3.0
        double u = ((double)tid - 14.5) / sh_;             // (kh-1)/2 = 14.5
        s_gh[tid] = exp(-(u * u) / 2.0) / (sh_ * sqrt(2.0 * M_PI));
    } else if (tid >= 64 && tid < 64 + KW) {
        int t = tid - 64;
        const double sw_ = (2.0 * 1216.0 / 49.0) / 3.0;
        double u = ((double)t - 24.0) / sw_;               // (kw-1)/2 = 24.0
        s_gw[t] = exp(-(u * u) / 2.0) / (sw_ * sqrt(2.0 * M_PI));
    }
    __syncthreads();
    if (tid == 0) {
        double a = 0.0, c = 0.0;
        for (int t = 0; t < KH; ++t) a += s_gh[t];
        for (int t = 0; t < KW; ++t) c += s_gw[t];
        s_invS = 1.0 / (a * c);                            // 1/k.sum(); one fp64 divide
    }
    __syncthreads();
    const double invS = s_invS;
    for (int t = tid; t < NTAP; t += 256)
        wtab[t] = (float)((s_gh[t / KW] * s_gw[t % KW]) * invS);  // fp64->fp32 like numpy
}

// Fused kernel. Blocks [0, CONV_BLKS): one wave per (batch,i,j) sample point.
// All 23 taps/lane preloaded into registers (static indices -> no scratch),
// then one fp64 FMA chain in exact t-ascending per-lane order (bit-identical
// to the validated serial loop). No LDS, no per-block setup.
// Blocks [CONV_BLKS, ...): zero-fill out0 + NCHW->NHWC transpose.
__global__ __launch_bounds__(256) void k_fused(
    const float* __restrict__ gt, const float* __restrict__ dvf,
    const float* __restrict__ wtab,
    float* __restrict__ out0, float* __restrict__ out1, float* __restrict__ out2,
    float* __restrict__ vbuf, int* __restrict__ rcbuf)
{
#pragma clang fp contract(off)
    const int tid = threadIdx.x;

    if (blockIdx.x >= CONV_BLKS) {
        // ---- transpose + zero path ----
        const size_t idx = (size_t)(blockIdx.x - CONV_BLKS) * 256 + tid;  // over Bb*HWsz/4
        ((float4*)out0)[idx] = make_float4(0.0f, 0.0f, 0.0f, 0.0f);
        const int b = (int)(idx / (HWsz / 4));
        const int r = (int)(idx - (size_t)b * (HWsz / 4));
        const float4* p0 = (const float4*)(dvf + (size_t)b * 2 * HWsz);
        const float4* p1 = (const float4*)(dvf + (size_t)b * 2 * HWsz + HWsz);
        float4 a = p0[r], c = p1[r];
        float4* o = (float4*)(out1 + ((size_t)b * HWsz + (size_t)r * 4) * 2);
        o[0] = make_float4(a.x, c.x, a.y, c.y);
        o[1] = make_float4(a.z, c.z, a.w, c.w);
        return;
    }

    // ---- conv + sample path ----
    const int wave = tid >> 6, lane = tid & 63;
    const int pt = blockIdx.x * 4 + wave;                  // pt < NPTS exactly
    const int b = pt / NPB, p = pt - b * NPB;
    const int i = p / SWs, j = p - i * SWs;
    const int y0r = (i * 227) >> 4;                        // arange(16)*227//16
    const int x0c = (j * 1168) / 48;                       // arange(48)*1168//48
    const float* c0 = dvf + (size_t)b * (2 * HWsz) + y0r * Ww + x0c;
    const float* c1 = c0 + HWsz;

    // Preload: 22 full taps + 1 tail tap (valid for lane < 62). All register-resident.
    float wv[23], xa[23], xb[23];
#pragma unroll
    for (int k = 0; k < 22; ++k) {
        int t = lane + 64 * k;
        int dy = t / KW, dx = t - dy * KW;
        int off = dy * Ww + dx;
        wv[k] = wtab[t];
        xa[k] = c0[off];
        xb[k] = c1[off];
    }
    {
        int t = lane + 64 * 22;                            // 1408 + lane
        int tt = (t < NTAP) ? t : 0;                       // clamp: harmless in-bounds load
        int dy = tt / KW, dx = tt - dy * KW;
        int off = dy * Ww + dx;
        wv[22] = wtab[tt];
        xa[22] = c0[off];
        xb[22] = c1[off];
    }

    double a0 = 0.0, a1 = 0.0;
#pragma unroll
    for (int k = 0; k < 22; ++k) {
        double w = (double)wv[k];
        a0 += w * (double)xa[k];
        a1 += w * (double)xb[k];
    }
    if (lane < 62) {                                       // tail tap t=1408+lane < 1470
        double w = (double)wv[22];
        a0 += w * (double)xa[22];
        a1 += w * (double)xb[22];
    }
    for (int o = 32; o > 0; o >>= 1) {
        a0 += __shfl_down(a0, o);
        a1 += __shfl_down(a1, o);
    }

    if (lane == 0) {
        float sx = (float)a0, sy = (float)a1;              // smoothed (fp32, like ref conv out)
        // numpy linspace semantics: y = j*step + start, endpoint forced to stop.
        const double startw = -(47.0 / 48.0), stopw = 47.0 / 48.0;
        const double starth = -(15.0 / 16.0), stoph = 15.0 / 16.0;
        const double stepw = (stopw - startw) / 47.0;
        const double steph = (stoph - starth) / 15.0;
        float gwl = (j == SWs - 1) ? (float)stopw : (float)((double)j * stepw + startw);
        float ghl = (i == SHs - 1) ? (float)stoph : (float)((double)i * steph + starth);
        float gx = sx + gwl;
        float gy = sy + ghl;

        float* o2 = out2 + ((size_t)(b * SHs + i) * SWs + j) * 2;
        o2[0] = gx; o2[1] = gy;

        // bilinear: x = (gx+1)*W/2 - 0.5 with reference op order
        const float* gtb = gt + (size_t)b * HWsz;
        float xw = (gx + 1.0f) * 1216.0f; xw = xw / 2.0f; xw = xw - 0.5f;
        float yw = (gy + 1.0f) * 256.0f;  yw = yw / 2.0f; yw = yw - 0.5f;
        float x0f = floorf(xw), y0f = floorf(yw);
        float x1f = x0f + 1.0f, y1f = y0f + 1.0f;
        float wx1 = xw - x0f, wx0 = 1.0f - wx1;
        float wy1 = yw - y0f, wy0 = 1.0f - wy1;
        float v = samp4(gtb, y0f, x0f, wy0 * wx0) + samp4(gtb, y0f, x1f, wy0 * wx1)
                + samp4(gtb, y1f, x0f, wy1 * wx0) + samp4(gtb, y1f, x1f, wy1 * wx1);

        // scatter coords: trunc toward zero (astype(int32)) THEN clip
        float rf = (gy + 1.0f) / 2.0f * 256.0f;
        float cf = (gx + 1.0f) / 2.0f * 1216.0f;
        int row = (int)rf; row = row < 0 ? 0 : (row > Hh - 1 ? Hh - 1 : row);
        int col = (int)cf; col = col < 0 ? 0 : (col > Ww - 1 ? Ww - 1 : col);
        vbuf[pt]  = v;
        rcbuf[pt] = (row << 16) | col;
    }
}

// Parallel last-write-wins scatter: point p writes iff no later point p' (same batch)
// targets the same (row,col) — identical result to serial in-order replay. Rows < 96
// skipped (reference zeroes them after the scatter).
__global__ __launch_bounds__(256) void k_scatter(
    const float* __restrict__ vbuf, const int* __restrict__ rcbuf, float* __restrict__ out0)
{
    __shared__ float sv[NPB];
    __shared__ int   sr[NPB];
    const int b = blockIdx.x, tid = threadIdx.x;
    for (int t = tid; t < NPB; t += 256) {
        sv[t] = vbuf[b * NPB + t];
        sr[t] = rcbuf[b * NPB + t];
    }
    __syncthreads();
    float* o = out0 + (size_t)b * HWsz;
    for (int p = tid; p < NPB; p += 256) {
        int rc = sr[p];
        int r = rc >> 16;
        if (r < 96) continue;
        bool win = true;
        for (int q = p + 1; q < NPB; ++q) {
            if (sr[q] == rc) { win = false; break; }
        }
        if (win) o[r * Ww + (rc & 0xffff)] = sv[p];
    }
}

extern "C" void kernel_launch(void* const* d_in, const int* in_sizes, int n_in,
                              void* d_out, int out_size, void* d_ws, size_t ws_size,
                              hipStream_t stream) {
    const float* gt  = (const float*)d_in[0];
    const float* dvf = (const float*)d_in[1];
    float* out0 = (float*)d_out;
    float* out1 = out0 + OUT0;
    float* out2 = out1 + OUT1;
    float* vbuf  = (float*)d_ws;              // NPTS floats
    int*   rcbuf = (int*)d_ws + NPTS;         // NPTS ints
    float* wtab  = (float*)d_ws + 2 * NPTS;   // NTAP floats (total ~198 KiB of ws)

    hipLaunchKernelGGL(k_weights, dim3(1), dim3(256), 0, stream, wtab);
    hipLaunchKernelGGL(k_fused, dim3(CONV_BLKS + TPOS_BLKS), dim3(256), 0, stream,
                       gt, dvf, wtab, out0, out1, out2, vbuf, rcbuf);
    hipLaunchKernelGGL(k_scatter, dim3(Bb), dim3(256), 0, stream,
                       vbuf, rcbuf, out0);
}